// Round 6
// baseline (347.359 us; speedup 1.0000x reference)
//
#include <hip/hip_runtime.h>

#define BATCH 16
#define LQ    1024
#define LK    1024
#define DD    512

typedef unsigned int u32;
typedef unsigned short ushort_t;
typedef short short8 __attribute__((ext_vector_type(8)));
typedef float f32x4 __attribute__((ext_vector_type(4)));
#define AS1 __attribute__((address_space(1)))
#define AS3 __attribute__((address_space(3)))

// ---------------------------------------------------------------------------
// split fp32 pair -> packed bf16 hi (truncation) and bf16 lo (= x - hi)
// ---------------------------------------------------------------------------
__device__ __forceinline__ void split2(float x0, float x1, u32& hp, u32& lp) {
    u32 u0 = __float_as_uint(x0), u1 = __float_as_uint(x1);
    hp = __builtin_amdgcn_perm(u1, u0, 0x07060302u);
    float l0 = x0 - __uint_as_float(u0 & 0xffff0000u);
    float l1 = x1 - __uint_as_float(u1 & 0xffff0000u);
    lp = __builtin_amdgcn_perm(__float_as_uint(l1), __float_as_uint(l0), 0x07060302u);
}

// fp32 pair -> packed bf16 (round-to-nearest-even), no lo
__device__ __forceinline__ u32 rne2(float x0, float x1) {
    u32 u0 = __float_as_uint(x0), u1 = __float_as_uint(x1);
    u0 += 0x7fffu + ((u0 >> 16) & 1u);
    u1 += 0x7fffu + ((u1 >> 16) & 1u);
    return __builtin_amdgcn_perm(u1, u0, 0x07060302u);
}

// ---------------------------------------------------------------------------
// V [LK x DD] fp32 -> Vt_hi / Vt_lo [DD x LK] bf16. grid (DD/32, LK/32, BATCH)
// ---------------------------------------------------------------------------
__global__ __launch_bounds__(256) void transpose_split_v(const float* __restrict__ V,
                                                         ushort_t* __restrict__ vthi,
                                                         ushort_t* __restrict__ vtlo) {
    __shared__ float tile[32][33];
    const int b = blockIdx.z;
    const int c0 = blockIdx.x * 32;   // d
    const int r0 = blockIdx.y * 32;   // kv
    const int t = threadIdx.x;
    const int r = t >> 3, c4 = (t & 7) * 4;
    const float* Vb = V + (size_t)b * LK * DD;
    float4 f = *(const float4*)(Vb + (size_t)(r0 + r) * DD + c0 + c4);
    tile[r][c4 + 0] = f.x; tile[r][c4 + 1] = f.y;
    tile[r][c4 + 2] = f.z; tile[r][c4 + 3] = f.w;
    __syncthreads();
    const int n = t >> 3, k4 = (t & 7) * 4;
    float x0 = tile[k4 + 0][n], x1 = tile[k4 + 1][n];
    float x2 = tile[k4 + 2][n], x3 = tile[k4 + 3][n];
    u32 h0, h1, l0, l1;
    split2(x0, x1, h0, l0); split2(x2, x3, h1, l1);
    size_t o = (size_t)b * DD * LK + (size_t)(c0 + n) * LK + r0 + k4;
    uint2 hv; hv.x = h0; hv.y = h1;
    uint2 lv; lv.x = l0; lv.y = l1;
    *(uint2*)(vthi + o) = hv;
    *(uint2*)(vtlo + o) = lv;
}

// ---------------------------------------------------------------------------
// QK GEMM, 3-pass split-bf16, split-on-stage:
//   S[1024 x 1024] = Q[1024 x 512] @ V[1024 x 512]^T  per batch
// 128x128 tile, BK=32, 4 waves. LDS rows 64 B = 4 chunks(16B);
// swizzle: phys chunk = logical ^ ((row>>1)&3)  [R3-verified conflict-free:
// each 8-lane b128 service group hits 8 distinct bank quads].
// Row steps of 8 (staging) and 16 (frags) keep (row>>1)&3 invariant.
// ---------------------------------------------------------------------------
__global__ __launch_bounds__(256) void gemm_qk(const float* __restrict__ Q,
                                               const float* __restrict__ V,
                                               float* __restrict__ S) {
    constexpr int KG = DD, NG = LK;
    __shared__ ushort_t sm[4][128 * 32];   // Ahi, Alo, Bhi, Blo = 32 KB

    const int b   = blockIdx.z;
    const int bm0 = blockIdx.x * 128;
    const int bn0 = blockIdx.y * 128;
    const int tid = threadIdx.x;
    const int w   = tid >> 6;
    const int lane = tid & 63;

    const int op   = w >> 1;
    const int woff = (w & 1) * 64;
    const int srow = woff + (lane >> 3);
    const int h    = lane & 7;                // half-chunk (8B) within 64B row
    const float* gsrc = (op == 0)
        ? Q + (size_t)b * LQ * KG + (size_t)(bm0 + srow) * KG
        : V + (size_t)b * LK * KG + (size_t)(bn0 + srow) * KG;
    gsrc += h * 4;
    const int wbase = srow * 32 + (((h >> 1) ^ ((srow >> 1) & 3)) * 8) + (h & 1) * 4;
    ushort_t* wp_hi = &sm[op * 2 + 0][wbase];
    ushort_t* wp_lo = &sm[op * 2 + 1][wbase];

    const int mf = lane & 15, q = lane >> 4;
    const int qx = (q ^ ((mf >> 1) & 3)) * 8;   // conflict-free frag chunk
    const int wm = (w & 1) * 64, wn = (w >> 1) * 64;

    f32x4 acc[4][4] = {};
    float4 st[8];

    auto load_tile = [&](int k) {
#pragma unroll
        for (int t = 0; t < 8; ++t)
            st[t] = *(const float4*)(gsrc + k + (size_t)t * 8 * KG);
    };

    load_tile(0);
    for (int k0 = 0; k0 < KG; k0 += 32) {
#pragma unroll
        for (int t = 0; t < 8; ++t) {
            u32 h01, h23, l01, l23;
            split2(st[t].x, st[t].y, h01, l01);
            split2(st[t].z, st[t].w, h23, l23);
            uint2 hv; hv.x = h01; hv.y = h23;
            uint2 lv; lv.x = l01; lv.y = l23;
            *(uint2*)(wp_hi + t * 256) = hv;
            *(uint2*)(wp_lo + t * 256) = lv;
        }
        if (k0 + 32 < KG) load_tile(k0 + 32);
        __syncthreads();                         // tile staged

        short8 ah[4], al[4];
#pragma unroll
        for (int i = 0; i < 4; ++i) {
            ah[i] = *(const short8*)&sm[0][(wm + mf + 16 * i) * 32 + qx];
            al[i] = *(const short8*)&sm[1][(wm + mf + 16 * i) * 32 + qx];
        }
#pragma unroll
        for (int j = 0; j < 4; ++j) {
            short8 bh = *(const short8*)&sm[2][(wn + mf + 16 * j) * 32 + qx];
            short8 bl = *(const short8*)&sm[3][(wn + mf + 16 * j) * 32 + qx];
#pragma unroll
            for (int i = 0; i < 4; ++i) {
                acc[i][j] = __builtin_amdgcn_mfma_f32_16x16x32_bf16(ah[i], bh, acc[i][j], 0, 0, 0);
                acc[i][j] = __builtin_amdgcn_mfma_f32_16x16x32_bf16(ah[i], bl, acc[i][j], 0, 0, 0);
                acc[i][j] = __builtin_amdgcn_mfma_f32_16x16x32_bf16(al[i], bh, acc[i][j], 0, 0, 0);
            }
        }
        __syncthreads();                         // frag reads done before overwrite
    }

    float* Sb = S + (size_t)b * LQ * NG + (size_t)bm0 * NG + bn0;
#pragma unroll
    for (int i = 0; i < 4; ++i)
#pragma unroll
        for (int j = 0; j < 4; ++j)
#pragma unroll
            for (int r = 0; r < 4; ++r)
                Sb[(size_t)(wm + i * 16 + q * 4 + r) * NG + wn + j * 16 + mf] = acc[i][j][r];
}

// ---------------------------------------------------------------------------
// Softmax (one wave per row) in place + pack P to bf16 (RNE). grid 16384/4.
// ---------------------------------------------------------------------------
__global__ __launch_bounds__(256) void softmax_pack(float* __restrict__ S,
                                                    ushort_t* __restrict__ Pbf) {
    const int w = threadIdx.x >> 6, lane = threadIdx.x & 63;
    const size_t row = (size_t)blockIdx.x * 4 + w;
    float* p = S + row * LK;

    float4 v[4];
#pragma unroll
    for (int t = 0; t < 4; ++t) v[t] = *(float4*)(p + lane * 4 + t * 256);

    float m = -3.0e38f;
#pragma unroll
    for (int t = 0; t < 4; ++t)
        m = fmaxf(m, fmaxf(fmaxf(v[t].x, v[t].y), fmaxf(v[t].z, v[t].w)));
#pragma unroll
    for (int off = 1; off < 64; off <<= 1)
        m = fmaxf(m, __shfl_xor(m, off, 64));

    float s = 0.f;
#pragma unroll
    for (int t = 0; t < 4; ++t) {
        v[t].x = __expf(v[t].x - m); v[t].y = __expf(v[t].y - m);
        v[t].z = __expf(v[t].z - m); v[t].w = __expf(v[t].w - m);
        s += (v[t].x + v[t].y) + (v[t].z + v[t].w);
    }
#pragma unroll
    for (int off = 1; off < 64; off <<= 1)
        s += __shfl_xor(s, off, 64);

    const float inv = 1.0f / s;
#pragma unroll
    for (int t = 0; t < 4; ++t) {
        v[t].x *= inv; v[t].y *= inv; v[t].z *= inv; v[t].w *= inv;
        *(float4*)(p + lane * 4 + t * 256) = v[t];
        uint2 hv;
        hv.x = rne2(v[t].x, v[t].y);
        hv.y = rne2(v[t].z, v[t].w);
        *(uint2*)(Pbf + row * LK + lane * 4 + t * 256) = hv;
    }
}

// ---------------------------------------------------------------------------
// PV GEMM, 2-pass (Phi*(Vhi+Vlo)), pure bf16 operands staged by
// global_load_lds (no staging VALU / ds_writes), double-buffered LDS,
// ONE barrier per K-step (prefetch has the whole step in flight).
//   C[1024 x 512] = P[1024 x 1024] @ Vt[512 x 1024]^T  per batch
// Source-side swizzle (16B chunks, 4/row): logical = (L&3)^((L>>3)&3)
// so LDS phys chunk = logical ^ ((row>>1)&3)  [R3-verified, 0 conflicts].
// ---------------------------------------------------------------------------
__global__ __launch_bounds__(256) void gemm_pv2(const ushort_t* __restrict__ P,
                                                const ushort_t* __restrict__ Vh,
                                                const ushort_t* __restrict__ Vl,
                                                float* __restrict__ C) {
    constexpr int KG = LK, NG = DD;
    __shared__ ushort_t sm[2][3][128 * 32];   // [buf][Phi,Vhi,Vlo] = 48 KB

    const int b   = blockIdx.z;
    const int bm0 = blockIdx.x * 128;
    const int bn0 = blockIdx.y * 128;
    const int tid = threadIdx.x;
    const int w   = tid >> 6;
    const int lane = tid & 63;

    const int lr = lane >> 2;                         // row within 16-row group
    const int lc = ((lane & 3) ^ ((lane >> 3) & 3)) * 8;  // swizzled src chunk
    const ushort_t* Pb  = P  + (size_t)b * LQ * KG + (size_t)bm0 * KG;
    const ushort_t* Vhb = Vh + (size_t)b * NG * KG + (size_t)bn0 * KG;
    const ushort_t* Vlb = Vl + (size_t)b * NG * KG + (size_t)bn0 * KG;

    const int mf = lane & 15, q = lane >> 4;
    const int qx = (q ^ ((mf >> 1) & 3)) * 8;
    const int wm = (w & 1) * 64, wn = (w >> 1) * 64;

    f32x4 acc[4][4] = {};

    // 24 stage slots (3 comps x 8 row-groups); wave w does slots [6w, 6w+6)
    auto stage = [&](int pb, int k) {
#pragma unroll
        for (int u = 0; u < 6; ++u) {
            const int s = w * 6 + u;
            const int comp = s >> 3;
            const int r16  = (s & 7) * 16;
            const ushort_t* g = (comp == 0) ? Pb : (comp == 1) ? Vhb : Vlb;
            g += (size_t)(r16 + lr) * KG + lc + k;
            __builtin_amdgcn_global_load_lds((const AS1 u32*)g,
                                             (AS3 u32*)(&sm[pb][0][0] + comp * 4096 + r16 * 32),
                                             16, 0, 0);
        }
    };

    stage(0, 0);
    int p = 0;
    for (int k0 = 0; k0 < KG; k0 += 32) {
        __syncthreads();                       // drains stage into sm[p]; guards sm[p^1]
        if (k0 + 32 < KG) stage(p ^ 1, k0 + 32);

        short8 ah[4];
#pragma unroll
        for (int i = 0; i < 4; ++i)
            ah[i] = *(const short8*)&sm[p][0][(wm + mf + 16 * i) * 32 + qx];
#pragma unroll
        for (int j = 0; j < 4; ++j) {
            short8 bh = *(const short8*)&sm[p][1][(wn + mf + 16 * j) * 32 + qx];
            short8 bl = *(const short8*)&sm[p][2][(wn + mf + 16 * j) * 32 + qx];
#pragma unroll
            for (int i = 0; i < 4; ++i) {
                acc[i][j] = __builtin_amdgcn_mfma_f32_16x16x32_bf16(ah[i], bh, acc[i][j], 0, 0, 0);
                acc[i][j] = __builtin_amdgcn_mfma_f32_16x16x32_bf16(ah[i], bl, acc[i][j], 0, 0, 0);
            }
        }
        p ^= 1;
    }

    float* Cb = C + (size_t)b * LQ * NG + (size_t)bm0 * NG + bn0;
#pragma unroll
    for (int i = 0; i < 4; ++i)
#pragma unroll
        for (int j = 0; j < 4; ++j)
#pragma unroll
            for (int r = 0; r < 4; ++r)
                Cb[(size_t)(wm + i * 16 + q * 4 + r) * NG + wn + j * 16 + mf] = acc[i][j][r];
}

// ===========================================================================
// Fallback fp32 path — used only if ws_size is too small (needs 67 MB)
// ===========================================================================
constexpr int BM = 64, BN = 64, BK = 16, PAD = 4;

__global__ __launch_bounds__(256) void gemm_qvt_f32(const float* __restrict__ Q,
                                                    const float* __restrict__ V,
                                                    float* __restrict__ S) {
    __shared__ __align__(16) float sA[BK][BM + PAD];
    __shared__ __align__(16) float sB[BK][BN + PAD];
    const int b = blockIdx.z;
    const float* Qb = Q + (size_t)b * LQ * DD + (size_t)blockIdx.x * BM * DD;
    const float* Vb = V + (size_t)b * LK * DD + (size_t)blockIdx.y * BN * DD;
    float*       Sb = S + (size_t)b * LQ * LK;
    const int tid = threadIdx.x;
    const int tx = tid & 15, ty = tid >> 4;
    const int lr = tid >> 2, lc = (tid & 3) << 2;
    float acc[4][4] = {};
    for (int k0 = 0; k0 < DD; k0 += BK) {
        float4 qa = *(const float4*)(Qb + (size_t)lr * DD + k0 + lc);
        float4 va = *(const float4*)(Vb + (size_t)lr * DD + k0 + lc);
        __syncthreads();
        sA[lc + 0][lr] = qa.x; sA[lc + 1][lr] = qa.y; sA[lc + 2][lr] = qa.z; sA[lc + 3][lr] = qa.w;
        sB[lc + 0][lr] = va.x; sB[lc + 1][lr] = va.y; sB[lc + 2][lr] = va.z; sB[lc + 3][lr] = va.w;
        __syncthreads();
#pragma unroll
        for (int k = 0; k < BK; ++k) {
            float4 a4 = *(const float4*)&sA[k][ty << 2];
            float4 b4 = *(const float4*)&sB[k][tx << 2];
            float a[4] = {a4.x, a4.y, a4.z, a4.w};
            float bb[4] = {b4.x, b4.y, b4.z, b4.w};
#pragma unroll
            for (int i = 0; i < 4; ++i)
#pragma unroll
                for (int j = 0; j < 4; ++j) acc[i][j] = fmaf(a[i], bb[j], acc[i][j]);
        }
    }
    const int r0 = blockIdx.x * BM + (ty << 2), c0 = blockIdx.y * BN + (tx << 2);
#pragma unroll
    for (int i = 0; i < 4; ++i) {
        float4 o = {acc[i][0], acc[i][1], acc[i][2], acc[i][3]};
        *(float4*)(Sb + (size_t)(r0 + i) * LK + c0) = o;
    }
}

__global__ __launch_bounds__(256) void softmax_wave(float* __restrict__ S) {
    const int w = threadIdx.x >> 6, lane = threadIdx.x & 63;
    float* p = S + ((size_t)blockIdx.x * 4 + w) * LK;
    float4 v[4];
#pragma unroll
    for (int t = 0; t < 4; ++t) v[t] = *(float4*)(p + lane * 4 + t * 256);
    float m = -3.0e38f;
#pragma unroll
    for (int t = 0; t < 4; ++t)
        m = fmaxf(m, fmaxf(fmaxf(v[t].x, v[t].y), fmaxf(v[t].z, v[t].w)));
#pragma unroll
    for (int off = 1; off < 64; off <<= 1) m = fmaxf(m, __shfl_xor(m, off, 64));
    float s = 0.f;
#pragma unroll
    for (int t = 0; t < 4; ++t) {
        v[t].x = __expf(v[t].x - m); v[t].y = __expf(v[t].y - m);
        v[t].z = __expf(v[t].z - m); v[t].w = __expf(v[t].w - m);
        s += (v[t].x + v[t].y) + (v[t].z + v[t].w);
    }
#pragma unroll
    for (int off = 1; off < 64; off <<= 1) s += __shfl_xor(s, off, 64);
    const float inv = 1.0f / s;
#pragma unroll
    for (int t = 0; t < 4; ++t) {
        v[t].x *= inv; v[t].y *= inv; v[t].z *= inv; v[t].w *= inv;
        *(float4*)(p + lane * 4 + t * 256) = v[t];
    }
}

__global__ __launch_bounds__(256) void gemm_pv_f32(const float* __restrict__ P,
                                                   const float* __restrict__ V,
                                                   float* __restrict__ C) {
    __shared__ __align__(16) float sA[BK][BM + PAD];
    __shared__ __align__(16) float sB[BK][BN + PAD];
    const int b = blockIdx.z;
    const float* Pb = P + (size_t)b * LQ * LK + (size_t)blockIdx.x * BM * LK;
    const float* Vb = V + (size_t)b * LK * DD;
    float*       Cb = C + (size_t)b * LQ * DD;
    const int tid = threadIdx.x;
    const int tx = tid & 15, ty = tid >> 4;
    const int lr = tid >> 2, lc = (tid & 3) << 2;
    const int bkr = tid >> 4, bcg = (tid & 15) << 2;
    const int n0 = blockIdx.y * BN;
    float acc[4][4] = {};
    for (int k0 = 0; k0 < LK; k0 += BK) {
        float4 pa = *(const float4*)(Pb + (size_t)lr * LK + k0 + lc);
        float4 vb = *(const float4*)(Vb + (size_t)(k0 + bkr) * DD + n0 + bcg);
        __syncthreads();
        sA[lc + 0][lr] = pa.x; sA[lc + 1][lr] = pa.y; sA[lc + 2][lr] = pa.z; sA[lc + 3][lr] = pa.w;
        *(float4*)&sB[bkr][bcg] = vb;
        __syncthreads();
#pragma unroll
        for (int k = 0; k < BK; ++k) {
            float4 a4 = *(const float4*)&sA[k][ty << 2];
            float4 b4 = *(const float4*)&sB[k][tx << 2];
            float a[4] = {a4.x, a4.y, a4.z, a4.w};
            float bb[4] = {b4.x, b4.y, b4.z, b4.w};
#pragma unroll
            for (int i = 0; i < 4; ++i)
#pragma unroll
                for (int j = 0; j < 4; ++j) acc[i][j] = fmaf(a[i], bb[j], acc[i][j]);
        }
    }
    const int r0 = blockIdx.x * BM + (ty << 2), c0 = n0 + (tx << 2);
#pragma unroll
    for (int i = 0; i < 4; ++i) {
        float4 o = {acc[i][0], acc[i][1], acc[i][2], acc[i][3]};
        *(float4*)(Cb + (size_t)(r0 + i) * DD + c0) = o;
    }
}

// ---------------------------------------------------------------------------
extern "C" void kernel_launch(void* const* d_in, const int* in_sizes, int n_in,
                              void* d_out, int out_size, void* d_ws, size_t ws_size,
                              hipStream_t stream) {
    const float* Q = (const float*)d_in[0];
    const float* V = (const float*)d_in[1];

    float* ctx  = (float*)d_out;                       // [16,1024,512]
    float* attn = ctx + (size_t)BATCH * LQ * DD;       // [16,1024,1024]

    const size_t NVT = (size_t)BATCH * DD * LK;        // 8.4M
    const size_t NP  = (size_t)BATCH * LQ * LK;        // 16.8M
    const size_t needed = (2 * NVT + NP) * sizeof(ushort_t);   // 67 MB

    if (ws_size >= needed) {
        ushort_t* Vthi = (ushort_t*)d_ws;
        ushort_t* Vtlo = Vthi + NVT;
        ushort_t* Pbf  = Vtlo + NVT;

        transpose_split_v<<<dim3(DD / 32, LK / 32, BATCH), 256, 0, stream>>>(V, Vthi, Vtlo);
        gemm_qk<<<dim3(8, 8, BATCH), 256, 0, stream>>>(Q, V, attn);
        softmax_pack<<<dim3(BATCH * LQ / 4), 256, 0, stream>>>(attn, Pbf);
        gemm_pv2<<<dim3(8, 4, BATCH), 256, 0, stream>>>(Pbf, Vthi, Vtlo, ctx);
    } else {
        gemm_qvt_f32<<<dim3(LQ / BM, LK / BN, BATCH), 256, 0, stream>>>(Q, V, attn);
        softmax_wave<<<dim3(BATCH * LQ / 4), 256, 0, stream>>>(attn);
        gemm_pv_f32<<<dim3(LQ / BM, DD / BN, BATCH), 256, 0, stream>>>(attn, V, ctx);
    }
}